// Round 14
// baseline (199.133 us; speedup 1.0000x reference)
//
#include <hip/hip_runtime.h>
#include <hip/hip_fp16.h>

// SelfAttention: B=8, C=64, N=4096, d_head=8.
// o[b,c,m] = gamma * sum_n h[b,c,n] * softmax_n(f[:,n].g[:,m]) + x[b,c,m]
// R27 = R26 + merge-kernel ELIMINATED via split-K atomic tail fusion:
// both S=2 blocks of a (colblock,b) pair write Pacc/Lsum, threadfence
// (release), atomicAdd a per-pair counter (device-scope, m20); the last
// block threadfences (acquire, G16), reads only the PARTNER's Pacc half
// (own half stays in registers), combines, normalizes gamma/(lA+lB), and
// writes out = acc*s + x directly. Counters zeroed by proj block (0,0)
// (stream-ordered; re-zeroed every launch for graph replay).
// Note: ones-MFMA D rows are identical => accLA[0] holds l in EVERY lane.
// Session rules: no launch_bounds minwaves (R17/R22/R24 spill), BK=128 +
// vmcnt(4) (R19), 1-PAIR-ahead LDS pipeline (R21), paired-key hM + GLDS
// DMA (R15), coalesced proj epilogue (R21).

typedef _Float16 half8_t __attribute__((ext_vector_type(8)));
typedef _Float16 half4_t __attribute__((ext_vector_type(4)));
typedef _Float16 half2_t __attribute__((ext_vector_type(2)));
typedef __fp16  fp16x2  __attribute__((ext_vector_type(2)));
typedef float float4_t __attribute__((ext_vector_type(4)));
typedef unsigned int uintx4 __attribute__((ext_vector_type(4)));

#define NTOK 4096
#define PRH 72   // proj LDS row stride in halves
#define LOG2E 1.44269504088896340736f

#if __has_builtin(__builtin_amdgcn_exp2f)
__device__ __forceinline__ float fexp2(float x) { return __builtin_amdgcn_exp2f(x); }
#else
__device__ __forceinline__ float fexp2(float x) { return exp2f(x); }
#endif

__device__ __forceinline__ half2_t pkcvt(float a, float b) {
    fp16x2 v = __builtin_amdgcn_cvt_pkrtz(a, b);
    return __builtin_bit_cast(half2_t, v);
}

__device__ __forceinline__ float4_t mfma16(half4_t a, half4_t b, float4_t c) {
    return __builtin_amdgcn_mfma_f32_16x16x16f16(a, b, c, 0, 0, 0);
}
__device__ __forceinline__ float4_t mfma32(half8_t a, half8_t b, float4_t c) {
    return __builtin_amdgcn_mfma_f32_16x16x32_f16(a, b, c, 0, 0, 0);
}

#define GLDS(G, L) __builtin_amdgcn_global_load_lds(                            \
    (const __attribute__((address_space(1))) unsigned int*)(G),                 \
    (__attribute__((address_space(3))) unsigned int*)(L), 16, 0, 0)

// counted wait + raw barrier: the 4 tile-DMAs (issued first this iter) are
// retired; the 4 f-record loads (issued after) may stay in flight
#define WAITVM4_BAR() do {                                                      \
    __builtin_amdgcn_sched_barrier(0);                                          \
    asm volatile("s_waitcnt vmcnt(4)" ::: "memory");                            \
    __builtin_amdgcn_sched_barrier(0);                                          \
    __builtin_amdgcn_s_barrier();                                               \
} while (0)

// ---------------- projection (MFMA) ------------------------------------------
// grid (128 token-tiles of 32, 8 b), block 320 = 5 waves = 5 out-row-groups.
// wave0 rows = Wq(8)+Wk(8); waves1-4 = Wv rows. x staged transposed to LDS
// fp16 with XOR channel swizzle. fTR records: [b][kt64*16+ml][q][t4][4] halves;
// q>=2 slots are the K-pad constants. hM stored PAIRED (key = kt64*64+t4*16+ml,
// pos = (t4>>1)*32+(ml>>2)*8+(t4&1)*4+(ml&3)) so attn PV A-frags are b128.
// hM output staged via dead xh buffer -> coalesced 16B/lane stores.
// Block (0,0) also zeroes the 256 attn combine counters (runs before attn).
__global__ __launch_bounds__(320) void proj_kernel(
    const float* __restrict__ x,
    const float* __restrict__ Wq, const float* __restrict__ bq,
    const float* __restrict__ Wk, const float* __restrict__ bk,
    const float* __restrict__ Wv, const float* __restrict__ bv,
    __half* __restrict__ fTR, __half* __restrict__ gT16, __half* __restrict__ hM,
    int* __restrict__ cnt)
{
    __shared__ __align__(16) _Float16 xh[32 * PRH];   // 4.6 KB; reused as hstage[64][36]
    const int t      = threadIdx.x;
    const int blk    = blockIdx.x;
    const int b      = blockIdx.y;
    const int n0     = blk * 32;
    const int kt64   = blk >> 1;
    const int t4base = (blk & 1) * 2;

    if (blk == 0 && b == 0 && t < 256) cnt[t] = 0;

    // stage x[b][c][n0..+31] -> xh[tok][c ^ swz] fp16
    if (t < 256) {
#pragma unroll
        for (int i = 0; i < 2; i++) {
            const int idx = t + i * 256;
            const int c = idx >> 3, f4 = idx & 7;          // tokens f4*4..+3
            float4 v = *(const float4*)(x + (((size_t)(b * 64 + c)) << 12) + n0 + f4 * 4);
            const int cs = c ^ ((f4 & 3) << 4);
            xh[(f4 * 4 + 0) * PRH + cs] = (_Float16)v.x;
            xh[(f4 * 4 + 1) * PRH + cs] = (_Float16)v.y;
            xh[(f4 * 4 + 2) * PRH + cs] = (_Float16)v.z;
            xh[(f4 * 4 + 3) * PRH + cs] = (_Float16)v.w;
        }
    }

    const int w    = t >> 6;
    const int lane = t & 63;
    const int q    = lane >> 4;
    const int ml   = lane & 15;

    // A-frags: W row, k = ks*16 + q*4 + j
    const float* wrow;
    if (w == 0) wrow = (ml < 8) ? (Wq + ml * 64) : (Wk + (ml - 8) * 64);
    else        wrow = Wv + ((w - 1) * 16 + ml) * 64;
    half4_t afr[4];
#pragma unroll
    for (int ks = 0; ks < 4; ks++) {
        float4 wv4 = *(const float4*)(wrow + ks * 16 + q * 4);
        afr[ks] = (half4_t){(_Float16)wv4.x, (_Float16)wv4.y,
                            (_Float16)wv4.z, (_Float16)wv4.w};
    }
    float4 bias4;
    if (w == 0) bias4 = (q < 2) ? *(const float4*)(bq + q * 4)
                                : *(const float4*)(bk + (q - 2) * 4);
    else        bias4 = *(const float4*)(bv + (w - 1) * 16 + q * 4);

    __syncthreads();

    float4_t acc2[2];
#pragma unroll
    for (int cg = 0; cg < 2; cg++) {
        const int tok  = cg * 16 + ml;                  // local token
        const int swz  = (tok >> 2) & 3;
        float4_t acc = (float4_t){0.f, 0.f, 0.f, 0.f};
#pragma unroll
        for (int ks = 0; ks < 4; ks++) {
            half4_t bfr = *(const half4_t*)(&xh[tok * PRH + ((ks ^ swz) * 16 + q * 4)]);
            acc = __builtin_amdgcn_mfma_f32_16x16x16f16(afr[ks], bfr, acc, 0, 0, 0);
        }
        acc[0] += bias4.x; acc[1] += bias4.y; acc[2] += bias4.z; acc[3] += bias4.w;
        acc2[cg] = acc;
        const int gtok = n0 + tok;
        const int t4   = t4base + cg;

        if (w == 0) {
            __half* rec = fTR + ((size_t)b << 16) + (size_t)(kt64 * 16 + ml) * 64;
            if (q < 2) {
                half4_t fv = {(_Float16)(acc[0] * LOG2E), (_Float16)(acc[1] * LOG2E),
                              (_Float16)(acc[2] * LOG2E), (_Float16)(acc[3] * LOG2E)};
                *(half4_t*)(rec + q * 16 + t4 * 4) = fv;
            } else {
                // constant K-pad slots: q2 = {1,0,0,0}, q3 = zeros
                half4_t cv = (half4_t){};
                if (q == 2) cv[0] = (_Float16)1.0f;
                *(half4_t*)(rec + q * 16 + t4 * 4) = cv;
            }
            // g rows live in q>=2 lanes; gn2 via xor16 pairing (q2<->q3)
            float gn2p = acc[0] * acc[0] + acc[1] * acc[1] +
                         acc[2] * acc[2] + acc[3] * acc[3];
            float gn2 = gn2p + __shfl_xor(gn2p, 16, 64);
            if (q >= 2) {
                half4_t gv = {(_Float16)acc[0], (_Float16)acc[1],
                              (_Float16)acc[2], (_Float16)acc[3]};
                __half* gp = gT16 + (size_t)((b << 12) + gtok) * 16;
                *(half4_t*)(gp + (q - 2) * 4) = gv;
                if (q == 2) {
                    const float M = (LOG2E * 4.6f) * __builtin_sqrtf(gn2) + 1.0f;
                    *(half4_t*)(gp + 8) = (half4_t){(_Float16)(-M), 0, 0, 0};
                } else {
                    *(half4_t*)(gp + 12) = (half4_t){};
                }
            }
        }
    }

    // ---- hM epilogue: stage -> coalesced 16B/lane stores ----
    __syncthreads();   // all xh (MFMA B-frag) reads done; safe to overwrite
    if (w > 0) {
        const int ch = (w - 1) * 16 + q * 4;
#pragma unroll
        for (int cg = 0; cg < 2; cg++) {
            const int loc = ((ml >> 2) << 3) + (cg << 2) + (ml & 3);
#pragma unroll
            for (int r = 0; r < 4; r++)
                xh[(ch + r) * 36 + loc] = (_Float16)acc2[cg][r];
        }
    }
    __syncthreads();
    if (t < 256) {
        const int ch   = t >> 2;
        const int part = t & 3;
        half8_t v = *(const half8_t*)(&xh[ch * 36 + part * 8]);
        __half* dst = hM + ((size_t)(b * 64 + ch) << 12) + (size_t)kt64 * 64
                         + (blk & 1) * 32 + part * 8;
        *(half8_t*)dst = v;
    }
}

// ---------------- fused flash attention + split-K combine --------------------
// grid (32 colblocks of 128, 8 b, S), block 256 = 4 waves x 32 cols (2 tiles).
// BK=128 keys/iter; per iter: 16 QK mfma16 + 8 ones-l mfma32 + 32 PV mfma32,
// one barrier, 4 GLDS DMA, 4 f b128 loads, vmcnt(4) counted wait.
// ah LDS reads pipelined one PAIR ahead; QK interleaved between PAIRs.
// Tail: S=2 atomic last-block combine (see header); S=1 writes out directly.

#define LDAH(V0, V1, V2, V3, HP)                                                \
    half8_t V0 = *(const half8_t*)(HP);                                         \
    half8_t V1 = *(const half8_t*)((HP) + 1024);                                \
    half8_t V2 = *(const half8_t*)((HP) + 2048);                                \
    half8_t V3 = *(const half8_t*)((HP) + 3072);

#define QK(F, N)                                                                \
    float4_t N##A0, N##B0, N##A1, N##B1;                                        \
    {                                                                           \
        half4_t a0 = __builtin_shufflevector(F, F, 0, 1, 2, 3);                 \
        half4_t a1 = __builtin_shufflevector(F, F, 4, 5, 6, 7);                 \
        __builtin_amdgcn_s_setprio(1);                                          \
        N##A0 = mfma16(a0, gfA, z4);                                            \
        N##B0 = mfma16(a0, gfB, z4);                                            \
        N##A1 = mfma16(a1, gfA, z4);                                            \
        N##B1 = mfma16(a1, gfB, z4);                                            \
        __builtin_amdgcn_s_setprio(0);                                          \
    }

// h-frag params H0..H3 so N##A0 etc. paste with LITERAL tokens (R20 lesson)
#define PAIRC(N, H0, H1, H2, H3)                                                \
    {                                                                           \
        float eA0 = fexp2(N##A0[0]), eA1 = fexp2(N##A0[1]),                     \
              eA2 = fexp2(N##A0[2]), eA3 = fexp2(N##A0[3]);                     \
        float oA0 = fexp2(N##A1[0]), oA1 = fexp2(N##A1[1]),                     \
              oA2 = fexp2(N##A1[2]), oA3 = fexp2(N##A1[3]);                     \
        float eB0 = fexp2(N##B0[0]), eB1 = fexp2(N##B0[1]),                     \
              eB2 = fexp2(N##B0[2]), eB3 = fexp2(N##B0[3]);                     \
        float oB0 = fexp2(N##B1[0]), oB1 = fexp2(N##B1[1]),                     \
              oB2 = fexp2(N##B1[2]), oB3 = fexp2(N##B1[3]);                     \
        uintx4 puA = {__builtin_bit_cast(unsigned int, pkcvt(eA0, eA1)),        \
                      __builtin_bit_cast(unsigned int, pkcvt(eA2, eA3)),        \
                      __builtin_bit_cast(unsigned int, pkcvt(oA0, oA1)),        \
                      __builtin_bit_cast(unsigned int, pkcvt(oA2, oA3))};       \
        uintx4 puB = {__builtin_bit_cast(unsigned int, pkcvt(eB0, eB1)),        \
                      __builtin_bit_cast(unsigned int, pkcvt(eB2, eB3)),        \
                      __builtin_bit_cast(unsigned int, pkcvt(oB0, oB1)),        \
                      __builtin_bit_cast(unsigned int, pkcvt(oB2, oB3))};       \
        half8_t pA8 = __builtin_bit_cast(half8_t, puA);                         \
        half8_t pB8 = __builtin_bit_cast(half8_t, puB);                         \
        __builtin_amdgcn_s_setprio(1);                                          \
        accLA = mfma32(ones8, pA8, accLA);                                      \
        accLB = mfma32(ones8, pB8, accLB);                                      \
        accA[0] = mfma32(H0, pA8, accA[0]); accB[0] = mfma32(H0, pB8, accB[0]); \
        accA[1] = mfma32(H1, pA8, accA[1]); accB[1] = mfma32(H1, pB8, accB[1]); \
        accA[2] = mfma32(H2, pA8, accA[2]); accB[2] = mfma32(H2, pB8, accB[2]); \
        accA[3] = mfma32(H3, pA8, accA[3]); accB[3] = mfma32(H3, pB8, accB[3]); \
        __builtin_amdgcn_s_setprio(0);                                          \
    }

template<int NT, int S>
__global__ __launch_bounds__(256) void attn_kernel(
    const __half* __restrict__ fTR, const __half* __restrict__ gT16,
    const __half* __restrict__ hM,
    __half* __restrict__ Pacc, float* __restrict__ Lsum, int* __restrict__ cnt,
    const float* __restrict__ x, const float* __restrict__ gammap,
    float* __restrict__ out)
{
    __shared__ __align__(16) _Float16 hl[2][8192];  // 2 x 16 KB, [group][ch][64]
    const int tid   = threadIdx.x;
    const int w     = tid >> 6;
    const int lane  = tid & 63;
    const int q     = lane >> 4;
    const int ml    = lane & 15;
    const int m7    = ml & 7;
    const int b     = blockIdx.y;
    const int split = blockIdx.z;
    const int colA  = blockIdx.x * 128 + w * 16 + ml;
    const int colB  = colA + 64;

    half4_t gfA = *(const half4_t*)(gT16 + ((size_t)((b << 12) + colA)) * 16 + q * 4);
    half4_t gfB = *(const half4_t*)(gT16 + ((size_t)((b << 12) + colB)) * 16 + q * 4);

    float4_t accA[4], accB[4];
#pragma unroll
    for (int cg = 0; cg < 4; cg++) {
        accA[cg] = (float4_t){0.f, 0.f, 0.f, 0.f};
        accB[cg] = (float4_t){0.f, 0.f, 0.f, 0.f};
    }
    float4_t accLA = (float4_t){0.f, 0.f, 0.f, 0.f};
    float4_t accLB = (float4_t){0.f, 0.f, 0.f, 0.f};
    const half8_t ones8 = {(_Float16)1.0f, (_Float16)1.0f, (_Float16)1.0f,
                           (_Float16)1.0f, (_Float16)1.0f, (_Float16)1.0f,
                           (_Float16)1.0f, (_Float16)1.0f};
    const float4_t z4 = (float4_t){0.f, 0.f, 0.f, 0.f};

    const int k64 = split * NT * 2;        // first 64-key group index

    // DMA staging: lane-linear LDS dest (tid*16 B), XOR-swizzled global source.
    const int ch0  = tid >> 3;             // 0..31 (part0); part1 adds 32
    const int gsw  = (tid & 7) ^ (ch0 & 7);
    const __half* hs0 = hM + ((size_t)(b * 64 + ch0) << 12) + (size_t)k64 * 64 + gsw * 8;
    const __half* hs1 = hs0 + ((size_t)32 << 12);
    const __half* fptr = fTR + ((size_t)b << 16) + (size_t)(k64 * 16 + ml) * 64 + q * 16;

    // read-side swizzled group offsets (halves)
    const int gxa = ((q ^ m7) << 3);
    const int gxb = (((4 + q) ^ m7) << 3);

    // ---- prologue: DMA 128-key tile 0 + both f records; full drain once ----
    GLDS(hs0,      &hl[0][tid * 8]);
    GLDS(hs1,      &hl[0][2048 + tid * 8]);
    GLDS(hs0 + 64, &hl[0][4096 + tid * 8]);
    GLDS(hs1 + 64, &hl[0][6144 + tid * 8]);
    half8_t f01 = *(const half8_t*)fptr;
    half8_t f23 = *(const half8_t*)(fptr + 8);
    half8_t f45 = *(const half8_t*)(fptr + 1024);
    half8_t f67 = *(const half8_t*)(fptr + 1032);
    __syncthreads();

    const __half* hn0 = hs0 + 128;
    const __half* hn1 = hs1 + 128;

#pragma unroll 1
    for (int kt = 0; kt < NT; kt++) {
        const _Float16* hbA = &hl[kt & 1][ml << 6];
        const _Float16* hbB = hbA + 4096;

        // ---- pipelined body: LDAH one PAIR ahead; QK interleaved ----
        LDAH(a00, a01, a02, a03, hbA + gxa)
        QK(f01, s)

        // issue 4 GLDS for tile kt+1 (vmcnt order: [G x4][f x4])
        if (kt + 1 < NT) {
            _Float16* nb = &hl[(kt + 1) & 1][0];
            GLDS(hn0,      nb + tid * 8);
            GLDS(hn1,      nb + 2048 + tid * 8);
            GLDS(hn0 + 64, nb + 4096 + tid * 8);
            GLDS(hn1 + 64, nb + 6144 + tid * 8);
            hn0 += 128;
            hn1 += 128;
        }

        LDAH(a10, a11, a12, a13, hbA + gxb)
        QK(f23, t)

        PAIRC(s, a00, a01, a02, a03)

        LDAH(a20, a21, a22, a23, hbB + gxa)

        PAIRC(t, a10, a11, a12, a13)

        QK(f45, u)
        LDAH(a30, a31, a32, a33, hbB + gxb)

        PAIRC(u, a20, a21, a22, a23)

        QK(f67, v)
        // prefetch next iter's f records (after all f consumed)
        if (kt + 1 < NT) {
            f01 = *(const half8_t*)(fptr + 2048);
            f23 = *(const half8_t*)(fptr + 2056);
            f45 = *(const half8_t*)(fptr + 3072);
            f67 = *(const half8_t*)(fptr + 3080);
            fptr += 2048;
        }

        PAIRC(v, a30, a31, a32, a33)

        if (kt + 1 < NT) {
            WAITVM4_BAR();   // retires the 4 tile DMAs; f loads stay in flight
        }
    }

    const float gamma = gammap[0];

    if constexpr (S == 1) {
        // single split: normalize and write out directly (l in every lane)
        const float sA = gamma / accLA[0];
        const float sB = gamma / accLB[0];
#pragma unroll
        for (int cg = 0; cg < 4; cg++)
#pragma unroll
            for (int r = 0; r < 4; r++) {
                const int ch = cg * 16 + q * 4 + r;
                const size_t o1 = ((size_t)(b * 64 + ch) << 12) + colA;
                const size_t o2 = o1 + 64;
                out[o1] = accA[cg][r] * sA + x[o1];
                out[o2] = accB[cg][r] * sB + x[o2];
            }
        return;
    }

    // ---- S=2: write own partials, then atomic last-block combine ----
    __half* pa = Pacc + (((size_t)(split * 8 + b) * 64) << 12);
#pragma unroll
    for (int cg = 0; cg < 4; cg++)
#pragma unroll
        for (int r = 0; r < 4; r++) {
            int ch = cg * 16 + q * 4 + r;
            pa[((size_t)ch << 12) + colA] = __float2half(accA[cg][r]);
            pa[((size_t)ch << 12) + colB] = __float2half(accB[cg][r]);
        }
    if (q == 0) {
        Lsum[((size_t)(split * 8 + b) << 12) + colA] = accLA[0];
        Lsum[((size_t)(split * 8 + b) << 12) + colB] = accLB[0];
    }

    __threadfence();        // release: partials visible device-wide
    __syncthreads();        // all threads' fences complete before the atomic
    __shared__ int lastf;
    if (tid == 0)
        lastf = (atomicAdd(cnt + ((blockIdx.x << 3) | b), 1) == S - 1);
    __syncthreads();
    if (!lastf) return;
    __threadfence();        // acquire: partner's released writes visible

    const int os = 1 - split;
    const __half* pb = Pacc + (((size_t)(os * 8 + b) * 64) << 12);
    const float lA = accLA[0] + Lsum[((size_t)(os * 8 + b) << 12) + colA];
    const float lB = accLB[0] + Lsum[((size_t)(os * 8 + b) << 12) + colB];
    const float sA = gamma / lA;
    const float sB = gamma / lB;
#pragma unroll
    for (int cg = 0; cg < 4; cg++)
#pragma unroll
        for (int r = 0; r < 4; r++) {
            const int ch = cg * 16 + q * 4 + r;
            const size_t o1 = ((size_t)(b * 64 + ch) << 12) + colA;
            const size_t o2 = o1 + 64;
            const float vA = accA[cg][r] + __half2float(pb[((size_t)ch << 12) + colA]);
            const float vB = accB[cg][r] + __half2float(pb[((size_t)ch << 12) + colB]);
            out[o1] = vA * sA + x[o1];
            out[o2] = vB * sB + x[o2];
        }
}

extern "C" void kernel_launch(void* const* d_in, const int* in_sizes, int n_in,
                              void* d_out, int out_size, void* d_ws, size_t ws_size,
                              hipStream_t stream) {
    const float* x     = (const float*)d_in[0];
    const float* Wq    = (const float*)d_in[1];
    const float* bq    = (const float*)d_in[2];
    const float* Wk    = (const float*)d_in[3];
    const float* bk    = (const float*)d_in[4];
    const float* Wv    = (const float*)d_in[5];
    const float* bv    = (const float*)d_in[6];
    const float* gamma = (const float*)d_in[7];
    float* out = (float*)d_out;

    const size_t fr_bytes  = (size_t)8 * 65536 * 2;             // 1 MB (fTR, 4 q-slots)
    const size_t g_bytes   = (size_t)8 * NTOK * 16 * 2;         // 1 MB
    const size_t hM_bytes  = (size_t)8 * 64 * NTOK * 2;         // 4 MB
    const size_t pa_split  = (size_t)8 * 64 * NTOK * 2;         // 4 MB per split
    const size_t l_split   = (size_t)8 * NTOK * sizeof(float);  // 128 KB per split
    const size_t cnt_bytes = 1024;
    const size_t base_need = fr_bytes + g_bytes + hM_bytes;

    int S = 1;
    if (ws_size >= base_need + 2 * (pa_split + l_split) + cnt_bytes) S = 2;

    char* p = (char*)d_ws;
    __half* fTR  = (__half*)p;  p += fr_bytes;
    __half* gT16 = (__half*)p;  p += g_bytes;
    __half* hM   = (__half*)p;  p += hM_bytes;
    __half* Pacc = (__half*)p;  p += (size_t)2 * pa_split;
    float*  Lsum = (float*)p;   p += (size_t)2 * l_split;
    int*    cnt  = (int*)p;

    proj_kernel<<<dim3(128, 8), 320, 0, stream>>>(x, Wq, bq, Wk, bk, Wv, bv,
                                                  fTR, gT16, hM, cnt);
    if (S == 2) {
        attn_kernel<16, 2><<<dim3(32, 8, 2), 256, 0, stream>>>(
            fTR, gT16, hM, Pacc, Lsum, cnt, x, gamma, out);
    } else {
        attn_kernel<32, 1><<<dim3(32, 8, 1), 256, 0, stream>>>(
            fTR, gT16, hM, Pacc, Lsum, cnt, x, gamma, out);
    }
}

// Round 15
// 114.993 us; speedup vs baseline: 1.7317x; 1.7317x over previous
//
#include <hip/hip_runtime.h>
#include <hip/hip_fp16.h>

// SelfAttention: B=8, C=64, N=4096, d_head=8.
// o[b,c,m] = gamma * sum_n h[b,c,n] * softmax_n(f[:,n].g[:,m]) + x[b,c,m]
// R28 = R26 restored verbatim (champion: 113.98us). R27's fence-based merge
// fusion regressed 3.4x (device-scope threadfence = L2 writeback/invalidate
// per block on non-coherent-XCD hw) -- cross-block combine is structurally
// toxic here; the 7us merge kernel is cheap insurance.
// Session rules: no launch_bounds minwaves (R17/R22/R24 spill), BK=128 +
// vmcnt(4) counted wait (R19), 1-PAIR-ahead LDS pipeline (R21), paired-key
// hM + GLDS DMA staging (R15), coalesced proj epilogue (R21), S=2 (R26).

typedef _Float16 half8_t __attribute__((ext_vector_type(8)));
typedef _Float16 half4_t __attribute__((ext_vector_type(4)));
typedef _Float16 half2_t __attribute__((ext_vector_type(2)));
typedef __fp16  fp16x2  __attribute__((ext_vector_type(2)));
typedef float float4_t __attribute__((ext_vector_type(4)));
typedef unsigned int uintx4 __attribute__((ext_vector_type(4)));

#define NTOK 4096
#define PRH 72   // proj LDS row stride in halves
#define LOG2E 1.44269504088896340736f

#if __has_builtin(__builtin_amdgcn_exp2f)
__device__ __forceinline__ float fexp2(float x) { return __builtin_amdgcn_exp2f(x); }
#else
__device__ __forceinline__ float fexp2(float x) { return exp2f(x); }
#endif

__device__ __forceinline__ half2_t pkcvt(float a, float b) {
    fp16x2 v = __builtin_amdgcn_cvt_pkrtz(a, b);
    return __builtin_bit_cast(half2_t, v);
}

__device__ __forceinline__ float4_t mfma16(half4_t a, half4_t b, float4_t c) {
    return __builtin_amdgcn_mfma_f32_16x16x16f16(a, b, c, 0, 0, 0);
}
__device__ __forceinline__ float4_t mfma32(half8_t a, half8_t b, float4_t c) {
    return __builtin_amdgcn_mfma_f32_16x16x32_f16(a, b, c, 0, 0, 0);
}

#define GLDS(G, L) __builtin_amdgcn_global_load_lds(                            \
    (const __attribute__((address_space(1))) unsigned int*)(G),                 \
    (__attribute__((address_space(3))) unsigned int*)(L), 16, 0, 0)

// counted wait + raw barrier: the 4 tile-DMAs (issued first this iter) are
// retired; the 4 f-record loads (issued after) may stay in flight
#define WAITVM4_BAR() do {                                                      \
    __builtin_amdgcn_sched_barrier(0);                                          \
    asm volatile("s_waitcnt vmcnt(4)" ::: "memory");                            \
    __builtin_amdgcn_sched_barrier(0);                                          \
    __builtin_amdgcn_s_barrier();                                               \
} while (0)

// ---------------- projection (MFMA) ------------------------------------------
// grid (128 token-tiles of 32, 8 b), block 320 = 5 waves = 5 out-row-groups.
// wave0 rows = Wq(8)+Wk(8); waves1-4 = Wv rows. x staged transposed to LDS
// fp16 with XOR channel swizzle. fTR records: [b][kt64*16+ml][q][t4][4] halves;
// q>=2 slots are the K-pad constants. hM stored PAIRED (key = kt64*64+t4*16+ml,
// pos = (t4>>1)*32+(ml>>2)*8+(t4&1)*4+(ml&3)) so attn PV A-frags are b128.
// hM output staged via dead xh buffer -> coalesced 16B/lane stores.
__global__ __launch_bounds__(320) void proj_kernel(
    const float* __restrict__ x,
    const float* __restrict__ Wq, const float* __restrict__ bq,
    const float* __restrict__ Wk, const float* __restrict__ bk,
    const float* __restrict__ Wv, const float* __restrict__ bv,
    __half* __restrict__ fTR, __half* __restrict__ gT16, __half* __restrict__ hM)
{
    __shared__ __align__(16) _Float16 xh[32 * PRH];   // 4.6 KB; reused as hstage[64][36]
    const int t      = threadIdx.x;
    const int blk    = blockIdx.x;
    const int b      = blockIdx.y;
    const int n0     = blk * 32;
    const int kt64   = blk >> 1;
    const int t4base = (blk & 1) * 2;

    // stage x[b][c][n0..+31] -> xh[tok][c ^ swz] fp16
    if (t < 256) {
#pragma unroll
        for (int i = 0; i < 2; i++) {
            const int idx = t + i * 256;
            const int c = idx >> 3, f4 = idx & 7;          // tokens f4*4..+3
            float4 v = *(const float4*)(x + (((size_t)(b * 64 + c)) << 12) + n0 + f4 * 4);
            const int cs = c ^ ((f4 & 3) << 4);
            xh[(f4 * 4 + 0) * PRH + cs] = (_Float16)v.x;
            xh[(f4 * 4 + 1) * PRH + cs] = (_Float16)v.y;
            xh[(f4 * 4 + 2) * PRH + cs] = (_Float16)v.z;
            xh[(f4 * 4 + 3) * PRH + cs] = (_Float16)v.w;
        }
    }

    const int w    = t >> 6;
    const int lane = t & 63;
    const int q    = lane >> 4;
    const int ml   = lane & 15;

    // A-frags: W row, k = ks*16 + q*4 + j
    const float* wrow;
    if (w == 0) wrow = (ml < 8) ? (Wq + ml * 64) : (Wk + (ml - 8) * 64);
    else        wrow = Wv + ((w - 1) * 16 + ml) * 64;
    half4_t afr[4];
#pragma unroll
    for (int ks = 0; ks < 4; ks++) {
        float4 wv4 = *(const float4*)(wrow + ks * 16 + q * 4);
        afr[ks] = (half4_t){(_Float16)wv4.x, (_Float16)wv4.y,
                            (_Float16)wv4.z, (_Float16)wv4.w};
    }
    float4 bias4;
    if (w == 0) bias4 = (q < 2) ? *(const float4*)(bq + q * 4)
                                : *(const float4*)(bk + (q - 2) * 4);
    else        bias4 = *(const float4*)(bv + (w - 1) * 16 + q * 4);

    __syncthreads();

    float4_t acc2[2];
#pragma unroll
    for (int cg = 0; cg < 2; cg++) {
        const int tok  = cg * 16 + ml;                  // local token
        const int swz  = (tok >> 2) & 3;
        float4_t acc = (float4_t){0.f, 0.f, 0.f, 0.f};
#pragma unroll
        for (int ks = 0; ks < 4; ks++) {
            half4_t bfr = *(const half4_t*)(&xh[tok * PRH + ((ks ^ swz) * 16 + q * 4)]);
            acc = __builtin_amdgcn_mfma_f32_16x16x16f16(afr[ks], bfr, acc, 0, 0, 0);
        }
        acc[0] += bias4.x; acc[1] += bias4.y; acc[2] += bias4.z; acc[3] += bias4.w;
        acc2[cg] = acc;
        const int gtok = n0 + tok;
        const int t4   = t4base + cg;

        if (w == 0) {
            __half* rec = fTR + ((size_t)b << 16) + (size_t)(kt64 * 16 + ml) * 64;
            if (q < 2) {
                half4_t fv = {(_Float16)(acc[0] * LOG2E), (_Float16)(acc[1] * LOG2E),
                              (_Float16)(acc[2] * LOG2E), (_Float16)(acc[3] * LOG2E)};
                *(half4_t*)(rec + q * 16 + t4 * 4) = fv;
            } else {
                // constant K-pad slots: q2 = {1,0,0,0}, q3 = zeros
                half4_t cv = (half4_t){};
                if (q == 2) cv[0] = (_Float16)1.0f;
                *(half4_t*)(rec + q * 16 + t4 * 4) = cv;
            }
            // g rows live in q>=2 lanes; gn2 via xor16 pairing (q2<->q3)
            float gn2p = acc[0] * acc[0] + acc[1] * acc[1] +
                         acc[2] * acc[2] + acc[3] * acc[3];
            float gn2 = gn2p + __shfl_xor(gn2p, 16, 64);
            if (q >= 2) {
                half4_t gv = {(_Float16)acc[0], (_Float16)acc[1],
                              (_Float16)acc[2], (_Float16)acc[3]};
                __half* gp = gT16 + (size_t)((b << 12) + gtok) * 16;
                *(half4_t*)(gp + (q - 2) * 4) = gv;
                if (q == 2) {
                    const float M = (LOG2E * 4.6f) * __builtin_sqrtf(gn2) + 1.0f;
                    *(half4_t*)(gp + 8) = (half4_t){(_Float16)(-M), 0, 0, 0};
                } else {
                    *(half4_t*)(gp + 12) = (half4_t){};
                }
            }
        }
    }

    // ---- hM epilogue: stage -> coalesced 16B/lane stores ----
    __syncthreads();   // all xh (MFMA B-frag) reads done; safe to overwrite
    if (w > 0) {
        const int ch = (w - 1) * 16 + q * 4;
#pragma unroll
        for (int cg = 0; cg < 2; cg++) {
            const int loc = ((ml >> 2) << 3) + (cg << 2) + (ml & 3);
#pragma unroll
            for (int r = 0; r < 4; r++)
                xh[(ch + r) * 36 + loc] = (_Float16)acc2[cg][r];
        }
    }
    __syncthreads();
    if (t < 256) {
        const int ch   = t >> 2;
        const int part = t & 3;
        half8_t v = *(const half8_t*)(&xh[ch * 36 + part * 8]);
        __half* dst = hM + ((size_t)(b * 64 + ch) << 12) + (size_t)kt64 * 64
                         + (blk & 1) * 32 + part * 8;
        *(half8_t*)dst = v;
    }
}

// ---------------- fused flash attention (key-split, shifted softmax) ---------
// grid (32 colblocks of 128, 8 b, S), block 256 = 4 waves x 32 cols (2 tiles).
// BK=128 keys/iter; per iter: 16 QK mfma16 + 8 ones-l mfma32 + 32 PV mfma32,
// one barrier, 4 GLDS DMA, 4 f b128 loads, vmcnt(4) counted wait.
// ah LDS reads pipelined one PAIR ahead; QK interleaved between PAIRs.

#define LDAH(V0, V1, V2, V3, HP)                                                \
    half8_t V0 = *(const half8_t*)(HP);                                         \
    half8_t V1 = *(const half8_t*)((HP) + 1024);                                \
    half8_t V2 = *(const half8_t*)((HP) + 2048);                                \
    half8_t V3 = *(const half8_t*)((HP) + 3072);

#define QK(F, N)                                                                \
    float4_t N##A0, N##B0, N##A1, N##B1;                                        \
    {                                                                           \
        half4_t a0 = __builtin_shufflevector(F, F, 0, 1, 2, 3);                 \
        half4_t a1 = __builtin_shufflevector(F, F, 4, 5, 6, 7);                 \
        __builtin_amdgcn_s_setprio(1);                                          \
        N##A0 = mfma16(a0, gfA, z4);                                            \
        N##B0 = mfma16(a0, gfB, z4);                                            \
        N##A1 = mfma16(a1, gfA, z4);                                            \
        N##B1 = mfma16(a1, gfB, z4);                                            \
        __builtin_amdgcn_s_setprio(0);                                          \
    }

// h-frag params H0..H3 so N##A0 etc. paste with LITERAL tokens (R20 lesson)
#define PAIRC(N, H0, H1, H2, H3)                                                \
    {                                                                           \
        float eA0 = fexp2(N##A0[0]), eA1 = fexp2(N##A0[1]),                     \
              eA2 = fexp2(N##A0[2]), eA3 = fexp2(N##A0[3]);                     \
        float oA0 = fexp2(N##A1[0]), oA1 = fexp2(N##A1[1]),                     \
              oA2 = fexp2(N##A1[2]), oA3 = fexp2(N##A1[3]);                     \
        float eB0 = fexp2(N##B0[0]), eB1 = fexp2(N##B0[1]),                     \
              eB2 = fexp2(N##B0[2]), eB3 = fexp2(N##B0[3]);                     \
        float oB0 = fexp2(N##B1[0]), oB1 = fexp2(N##B1[1]),                     \
              oB2 = fexp2(N##B1[2]), oB3 = fexp2(N##B1[3]);                     \
        uintx4 puA = {__builtin_bit_cast(unsigned int, pkcvt(eA0, eA1)),        \
                      __builtin_bit_cast(unsigned int, pkcvt(eA2, eA3)),        \
                      __builtin_bit_cast(unsigned int, pkcvt(oA0, oA1)),        \
                      __builtin_bit_cast(unsigned int, pkcvt(oA2, oA3))};       \
        uintx4 puB = {__builtin_bit_cast(unsigned int, pkcvt(eB0, eB1)),        \
                      __builtin_bit_cast(unsigned int, pkcvt(eB2, eB3)),        \
                      __builtin_bit_cast(unsigned int, pkcvt(oB0, oB1)),        \
                      __builtin_bit_cast(unsigned int, pkcvt(oB2, oB3))};       \
        half8_t pA8 = __builtin_bit_cast(half8_t, puA);                         \
        half8_t pB8 = __builtin_bit_cast(half8_t, puB);                         \
        __builtin_amdgcn_s_setprio(1);                                          \
        accLA = mfma32(ones8, pA8, accLA);                                      \
        accLB = mfma32(ones8, pB8, accLB);                                      \
        accA[0] = mfma32(H0, pA8, accA[0]); accB[0] = mfma32(H0, pB8, accB[0]); \
        accA[1] = mfma32(H1, pA8, accA[1]); accB[1] = mfma32(H1, pB8, accB[1]); \
        accA[2] = mfma32(H2, pA8, accA[2]); accB[2] = mfma32(H2, pB8, accB[2]); \
        accA[3] = mfma32(H3, pA8, accA[3]); accB[3] = mfma32(H3, pB8, accB[3]); \
        __builtin_amdgcn_s_setprio(0);                                          \
    }

template<int NT>
__global__ __launch_bounds__(256) void attn_kernel(
    const __half* __restrict__ fTR, const __half* __restrict__ gT16,
    const __half* __restrict__ hM,
    __half* __restrict__ Pacc, float* __restrict__ Lsum)
{
    __shared__ __align__(16) _Float16 hl[2][8192];  // 2 x 16 KB, [group][ch][64]
    const int tid   = threadIdx.x;
    const int w     = tid >> 6;
    const int lane  = tid & 63;
    const int q     = lane >> 4;
    const int ml    = lane & 15;
    const int m7    = ml & 7;
    const int b     = blockIdx.y;
    const int split = blockIdx.z;
    const int colA  = blockIdx.x * 128 + w * 16 + ml;
    const int colB  = colA + 64;

    half4_t gfA = *(const half4_t*)(gT16 + ((size_t)((b << 12) + colA)) * 16 + q * 4);
    half4_t gfB = *(const half4_t*)(gT16 + ((size_t)((b << 12) + colB)) * 16 + q * 4);

    float4_t accA[4], accB[4];
#pragma unroll
    for (int cg = 0; cg < 4; cg++) {
        accA[cg] = (float4_t){0.f, 0.f, 0.f, 0.f};
        accB[cg] = (float4_t){0.f, 0.f, 0.f, 0.f};
    }
    float4_t accLA = (float4_t){0.f, 0.f, 0.f, 0.f};
    float4_t accLB = (float4_t){0.f, 0.f, 0.f, 0.f};
    const half8_t ones8 = {(_Float16)1.0f, (_Float16)1.0f, (_Float16)1.0f,
                           (_Float16)1.0f, (_Float16)1.0f, (_Float16)1.0f,
                           (_Float16)1.0f, (_Float16)1.0f};
    const float4_t z4 = (float4_t){0.f, 0.f, 0.f, 0.f};

    const int k64 = split * NT * 2;        // first 64-key group index

    // DMA staging: lane-linear LDS dest (tid*16 B), XOR-swizzled global source.
    const int ch0  = tid >> 3;             // 0..31 (part0); part1 adds 32
    const int gsw  = (tid & 7) ^ (ch0 & 7);
    const __half* hs0 = hM + ((size_t)(b * 64 + ch0) << 12) + (size_t)k64 * 64 + gsw * 8;
    const __half* hs1 = hs0 + ((size_t)32 << 12);
    const __half* fptr = fTR + ((size_t)b << 16) + (size_t)(k64 * 16 + ml) * 64 + q * 16;

    // read-side swizzled group offsets (halves)
    const int gxa = ((q ^ m7) << 3);
    const int gxb = (((4 + q) ^ m7) << 3);

    // ---- prologue: DMA 128-key tile 0 + both f records; full drain once ----
    GLDS(hs0,      &hl[0][tid * 8]);
    GLDS(hs1,      &hl[0][2048 + tid * 8]);
    GLDS(hs0 + 64, &hl[0][4096 + tid * 8]);
    GLDS(hs1 + 64, &hl[0][6144 + tid * 8]);
    half8_t f01 = *(const half8_t*)fptr;
    half8_t f23 = *(const half8_t*)(fptr + 8);
    half8_t f45 = *(const half8_t*)(fptr + 1024);
    half8_t f67 = *(const half8_t*)(fptr + 1032);
    __syncthreads();

    const __half* hn0 = hs0 + 128;
    const __half* hn1 = hs1 + 128;

#pragma unroll 1
    for (int kt = 0; kt < NT; kt++) {
        const _Float16* hbA = &hl[kt & 1][ml << 6];
        const _Float16* hbB = hbA + 4096;

        // ---- pipelined body: LDAH one PAIR ahead; QK interleaved ----
        LDAH(a00, a01, a02, a03, hbA + gxa)
        QK(f01, s)

        // issue 4 GLDS for tile kt+1 (vmcnt order: [G x4][f x4])
        if (kt + 1 < NT) {
            _Float16* nb = &hl[(kt + 1) & 1][0];
            GLDS(hn0,      nb + tid * 8);
            GLDS(hn1,      nb + 2048 + tid * 8);
            GLDS(hn0 + 64, nb + 4096 + tid * 8);
            GLDS(hn1 + 64, nb + 6144 + tid * 8);
            hn0 += 128;
            hn1 += 128;
        }

        LDAH(a10, a11, a12, a13, hbA + gxb)
        QK(f23, t)

        PAIRC(s, a00, a01, a02, a03)

        LDAH(a20, a21, a22, a23, hbB + gxa)

        PAIRC(t, a10, a11, a12, a13)

        QK(f45, u)
        LDAH(a30, a31, a32, a33, hbB + gxb)

        PAIRC(u, a20, a21, a22, a23)

        QK(f67, v)
        // prefetch next iter's f records (after all f consumed)
        if (kt + 1 < NT) {
            f01 = *(const half8_t*)(fptr + 2048);
            f23 = *(const half8_t*)(fptr + 2056);
            f45 = *(const half8_t*)(fptr + 3072);
            f67 = *(const half8_t*)(fptr + 3080);
            fptr += 2048;
        }

        PAIRC(v, a30, a31, a32, a33)

        if (kt + 1 < NT) {
            WAITVM4_BAR();   // retires the 4 tile DMAs; f loads stay in flight
        }
    }

    // ---- store UNNORMALIZED partials + l (from ones-MFMA accumulator) ----
    __half* pa = Pacc + (((size_t)(split * 8 + b) * 64) << 12);
#pragma unroll
    for (int cg = 0; cg < 4; cg++)
#pragma unroll
        for (int r = 0; r < 4; r++) {
            int ch = cg * 16 + q * 4 + r;
            pa[((size_t)ch << 12) + colA] = __float2half(accA[cg][r]);
            pa[((size_t)ch << 12) + colB] = __float2half(accB[cg][r]);
        }
    if (q == 0) {
        Lsum[((size_t)(split * 8 + b) << 12) + colA] = accLA[0];
        Lsum[((size_t)(split * 8 + b) << 12) + colB] = accLB[0];
    }
}

// ---------------- merge ------------------------------------------------------
// grid (64 col-tiles, 8 b, 4 ch-groups of 16), block 256 = 16 ch x 16 col-quads.
template<int S>
__global__ __launch_bounds__(256) void merge_kernel(
    const __half* __restrict__ Pacc, const float* __restrict__ Lsum,
    const float* __restrict__ x, const float* __restrict__ gammap,
    float* __restrict__ out)
{
    __shared__ float invL[64];
    const int tid  = threadIdx.x;
    const int c4   = tid & 15;
    const int chh  = tid >> 4;
    const int b    = blockIdx.y;
    const int col0 = blockIdx.x * 64;
    const int ch   = blockIdx.z * 16 + chh;

    if (tid < 64) {
        float L = 0.f;
#pragma unroll
        for (int s = 0; s < S; s++)
            L += Lsum[((size_t)(s * 8 + b) << 12) + col0 + tid];
        invL[tid] = gammap[0] / L;
    }
    __syncthreads();

    const int cc = c4 * 4;
    const size_t base = (((size_t)b * 64 + ch) << 12) + col0 + cc;
    float4 xv = *(const float4*)(x + base);
    float o0 = 0.f, o1 = 0.f, o2 = 0.f, o3 = 0.f;
#pragma unroll
    for (int s = 0; s < S; s++) {
        half4_t pv = *(const half4_t*)(Pacc +
            (((size_t)(s * 8 + b) * 64 + ch) << 12) + col0 + cc);
        o0 += (float)pv[0];
        o1 += (float)pv[1];
        o2 += (float)pv[2];
        o3 += (float)pv[3];
    }
    float4 ov;
    ov.x = o0 * invL[cc]     + xv.x;
    ov.y = o1 * invL[cc + 1] + xv.y;
    ov.z = o2 * invL[cc + 2] + xv.z;
    ov.w = o3 * invL[cc + 3] + xv.w;
    *(float4*)(out + base) = ov;
}

extern "C" void kernel_launch(void* const* d_in, const int* in_sizes, int n_in,
                              void* d_out, int out_size, void* d_ws, size_t ws_size,
                              hipStream_t stream) {
    const float* x     = (const float*)d_in[0];
    const float* Wq    = (const float*)d_in[1];
    const float* bq    = (const float*)d_in[2];
    const float* Wk    = (const float*)d_in[3];
    const float* bk    = (const float*)d_in[4];
    const float* Wv    = (const float*)d_in[5];
    const float* bv    = (const float*)d_in[6];
    const float* gamma = (const float*)d_in[7];
    float* out = (float*)d_out;

    const size_t fr_bytes  = (size_t)8 * 65536 * 2;             // 1 MB (fTR, 4 q-slots)
    const size_t g_bytes   = (size_t)8 * NTOK * 16 * 2;         // 1 MB
    const size_t hM_bytes  = (size_t)8 * 64 * NTOK * 2;         // 4 MB
    const size_t pa_split  = (size_t)8 * 64 * NTOK * 2;         // 4 MB per split
    const size_t l_split   = (size_t)8 * NTOK * sizeof(float);  // 128 KB per split
    const size_t base_need = fr_bytes + g_bytes + hM_bytes;

    int S = 1;
    if (ws_size >= base_need + 2 * (pa_split + l_split)) S = 2;

    char* p = (char*)d_ws;
    __half* fTR  = (__half*)p;  p += fr_bytes;
    __half* gT16 = (__half*)p;  p += g_bytes;
    __half* hM   = (__half*)p;  p += hM_bytes;
    __half* Pacc = (__half*)p;  p += (size_t)S * pa_split;
    float*  Lsum = (float*)p;

    proj_kernel<<<dim3(128, 8), 320, 0, stream>>>(x, Wq, bq, Wk, bk, Wv, bv,
                                                  fTR, gT16, hM);
    if (S == 2) {
        attn_kernel<16><<<dim3(32, 8, 2), 256, 0, stream>>>(fTR, gT16, hM, Pacc, Lsum);
        merge_kernel<2><<<dim3(64, 8, 4), 256, 0, stream>>>(Pacc, Lsum, x, gamma, out);
    } else {
        attn_kernel<32><<<dim3(32, 8, 1), 256, 0, stream>>>(fTR, gT16, hM, Pacc, Lsum);
        merge_kernel<1><<<dim3(64, 8, 4), 256, 0, stream>>>(Pacc, Lsum, x, gamma, out);
    }
}

// Round 17
// 113.396 us; speedup vs baseline: 1.7561x; 1.0141x over previous
//
#include <hip/hip_runtime.h>
#include <hip/hip_fp16.h>

// SelfAttention: B=8, C=64, N=4096, d_head=8.
// o[b,c,m] = gamma * sum_n h[b,c,n] * softmax_n(f[:,n].g[:,m]) + x[b,c,m]
// R30 = R29 resubmitted (prior round died on a container infra failure,
// not the kernel). proj processes 64 tokens/block: grid 1024->512 blocks,
// W/bias loads amortized 2x, 3 syncthreads per 64 (was per 32) tokens,
// full kt64 fTR/hM records per block. attn + merge byte-identical to the
// R28 champion (~114us).
// Session rules: no launch_bounds minwaves (R17/R22/R24 spill), BK=128 +
// vmcnt(4) (R19), 1-PAIR-ahead LDS pipeline (R21), paired-key hM + GLDS
// DMA (R15), S=2 + separate merge (R26; fusion toxic per R24/R27).

typedef _Float16 half8_t __attribute__((ext_vector_type(8)));
typedef _Float16 half4_t __attribute__((ext_vector_type(4)));
typedef _Float16 half2_t __attribute__((ext_vector_type(2)));
typedef __fp16  fp16x2  __attribute__((ext_vector_type(2)));
typedef float float4_t __attribute__((ext_vector_type(4)));
typedef unsigned int uintx4 __attribute__((ext_vector_type(4)));

#define NTOK 4096
#define PRH 72   // proj LDS row stride in halves
#define LOG2E 1.44269504088896340736f

#if __has_builtin(__builtin_amdgcn_exp2f)
__device__ __forceinline__ float fexp2(float x) { return __builtin_amdgcn_exp2f(x); }
#else
__device__ __forceinline__ float fexp2(float x) { return exp2f(x); }
#endif

__device__ __forceinline__ half2_t pkcvt(float a, float b) {
    fp16x2 v = __builtin_amdgcn_cvt_pkrtz(a, b);
    return __builtin_bit_cast(half2_t, v);
}

__device__ __forceinline__ float4_t mfma16(half4_t a, half4_t b, float4_t c) {
    return __builtin_amdgcn_mfma_f32_16x16x16f16(a, b, c, 0, 0, 0);
}
__device__ __forceinline__ float4_t mfma32(half8_t a, half8_t b, float4_t c) {
    return __builtin_amdgcn_mfma_f32_16x16x32_f16(a, b, c, 0, 0, 0);
}

#define GLDS(G, L) __builtin_amdgcn_global_load_lds(                            \
    (const __attribute__((address_space(1))) unsigned int*)(G),                 \
    (__attribute__((address_space(3))) unsigned int*)(L), 16, 0, 0)

// counted wait + raw barrier: the 4 tile-DMAs (issued first this iter) are
// retired; the 4 f-record loads (issued after) may stay in flight
#define WAITVM4_BAR() do {                                                      \
    __builtin_amdgcn_sched_barrier(0);                                          \
    asm volatile("s_waitcnt vmcnt(4)" ::: "memory");                            \
    __builtin_amdgcn_sched_barrier(0);                                          \
    __builtin_amdgcn_s_barrier();                                               \
} while (0)

// ---------------- projection (MFMA) ------------------------------------------
// grid (64 token-tiles of 64, 8 b), block 320 = 5 waves = 5 out-row-groups.
// wave0 rows = Wq(8)+Wk(8); waves1-4 = Wv rows. x staged transposed to LDS
// fp16 with XOR channel swizzle (4-way write conflicts). Each block covers a
// FULL kt64 = blk record: fTR [b][kt64*16+ml][q][t4=cg][4] halves (q>=2 =
// K-pad constants); hM PAIRED (key = kt64*64+t4*16+ml, pos = (t4>>1)*32 +
// (ml>>2)*8 + (t4&1)*4 + (ml&3)); hM re-staged via dead xh -> 16B/lane stores.
__global__ __launch_bounds__(320) void proj_kernel(
    const float* __restrict__ x,
    const float* __restrict__ Wq, const float* __restrict__ bq,
    const float* __restrict__ Wk, const float* __restrict__ bk,
    const float* __restrict__ Wv, const float* __restrict__ bv,
    __half* __restrict__ fTR, __half* __restrict__ gT16, __half* __restrict__ hM)
{
    __shared__ __align__(16) _Float16 xh[64 * PRH];   // 9.2 KB; reused as hstage[64][68]
    const int t    = threadIdx.x;
    const int blk  = blockIdx.x;       // 0..63
    const int b    = blockIdx.y;
    const int n0   = blk * 64;
    const int kt64 = blk;

    // stage x[b][c][n0..+63] -> xh[tok][c ^ swz] fp16 (4-way conflict pattern)
    if (t < 256) {
#pragma unroll
        for (int i = 0; i < 4; i++) {
            const int idx = t + (i & 1) * 256;           // 0..511
            const int c   = idx >> 3, f4l = idx & 7;     // c 0..63, tokens f4l*4..+3
            const int th  = (i >> 1) * 32;               // token-half offset
            float4 v = *(const float4*)(x + (((size_t)(b * 64 + c)) << 12)
                                          + n0 + th + f4l * 4);
            const int cs = c ^ ((f4l & 3) << 4);
            xh[(th + f4l * 4 + 0) * PRH + cs] = (_Float16)v.x;
            xh[(th + f4l * 4 + 1) * PRH + cs] = (_Float16)v.y;
            xh[(th + f4l * 4 + 2) * PRH + cs] = (_Float16)v.z;
            xh[(th + f4l * 4 + 3) * PRH + cs] = (_Float16)v.w;
        }
    }

    const int w    = t >> 6;
    const int lane = t & 63;
    const int q    = lane >> 4;
    const int ml   = lane & 15;

    // A-frags: W row, k = ks*16 + q*4 + j (loaded ONCE per 64 tokens)
    const float* wrow;
    if (w == 0) wrow = (ml < 8) ? (Wq + ml * 64) : (Wk + (ml - 8) * 64);
    else        wrow = Wv + ((w - 1) * 16 + ml) * 64;
    half4_t afr[4];
#pragma unroll
    for (int ks = 0; ks < 4; ks++) {
        float4 wv4 = *(const float4*)(wrow + ks * 16 + q * 4);
        afr[ks] = (half4_t){(_Float16)wv4.x, (_Float16)wv4.y,
                            (_Float16)wv4.z, (_Float16)wv4.w};
    }
    float4 bias4;
    if (w == 0) bias4 = (q < 2) ? *(const float4*)(bq + q * 4)
                                : *(const float4*)(bk + (q - 2) * 4);
    else        bias4 = *(const float4*)(bv + (w - 1) * 16 + q * 4);

    __syncthreads();

    float4_t acc2[4];
#pragma unroll
    for (int cg = 0; cg < 4; cg++) {
        const int tok  = cg * 16 + ml;                  // local token 0..63
        const int swz  = (tok >> 2) & 3;
        float4_t acc = (float4_t){0.f, 0.f, 0.f, 0.f};
#pragma unroll
        for (int ks = 0; ks < 4; ks++) {
            half4_t bfr = *(const half4_t*)(&xh[tok * PRH + ((ks ^ swz) * 16 + q * 4)]);
            acc = __builtin_amdgcn_mfma_f32_16x16x16f16(afr[ks], bfr, acc, 0, 0, 0);
        }
        acc[0] += bias4.x; acc[1] += bias4.y; acc[2] += bias4.z; acc[3] += bias4.w;
        acc2[cg] = acc;
        const int gtok = n0 + tok;
        const int t4   = cg;

        if (w == 0) {
            __half* rec = fTR + ((size_t)b << 16) + (size_t)(kt64 * 16 + ml) * 64;
            if (q < 2) {
                half4_t fv = {(_Float16)(acc[0] * LOG2E), (_Float16)(acc[1] * LOG2E),
                              (_Float16)(acc[2] * LOG2E), (_Float16)(acc[3] * LOG2E)};
                *(half4_t*)(rec + q * 16 + t4 * 4) = fv;
            } else {
                // constant K-pad slots: q2 = {1,0,0,0}, q3 = zeros
                half4_t cv = (half4_t){};
                if (q == 2) cv[0] = (_Float16)1.0f;
                *(half4_t*)(rec + q * 16 + t4 * 4) = cv;
            }
            // g rows live in q>=2 lanes; gn2 via xor16 pairing (q2<->q3)
            float gn2p = acc[0] * acc[0] + acc[1] * acc[1] +
                         acc[2] * acc[2] + acc[3] * acc[3];
            float gn2 = gn2p + __shfl_xor(gn2p, 16, 64);
            if (q >= 2) {
                half4_t gv = {(_Float16)acc[0], (_Float16)acc[1],
                              (_Float16)acc[2], (_Float16)acc[3]};
                __half* gp = gT16 + (size_t)((b << 12) + gtok) * 16;
                *(half4_t*)(gp + (q - 2) * 4) = gv;
                if (q == 2) {
                    const float M = (LOG2E * 4.6f) * __builtin_sqrtf(gn2) + 1.0f;
                    *(half4_t*)(gp + 8) = (half4_t){(_Float16)(-M), 0, 0, 0};
                } else {
                    *(half4_t*)(gp + 12) = (half4_t){};
                }
            }
        }
    }

    // ---- hM epilogue: stage full kt64 record -> coalesced 16B/lane stores ----
    __syncthreads();   // all xh (MFMA B-frag) reads done; safe to overwrite
    if (w > 0) {
        const int ch = (w - 1) * 16 + q * 4;
#pragma unroll
        for (int cg = 0; cg < 4; cg++) {
            const int pos = ((cg >> 1) << 5) + ((ml >> 2) << 3) + ((cg & 1) << 2) + (ml & 3);
#pragma unroll
            for (int r = 0; r < 4; r++)
                xh[(ch + r) * 68 + pos] = (_Float16)acc2[cg][r];
        }
    }
    __syncthreads();
    if (t < 256) {
#pragma unroll
        for (int i = 0; i < 2; i++) {
            const int idx  = t + i * 256;      // 0..511
            const int ch   = idx >> 3;
            const int part = idx & 7;
            half8_t v = *(const half8_t*)(&xh[ch * 68 + part * 8]);
            __half* dst = hM + ((size_t)(b * 64 + ch) << 12) + (size_t)kt64 * 64
                             + part * 8;
            *(half8_t*)dst = v;
        }
    }
}

// ---------------- fused flash attention (key-split, shifted softmax) ---------
// grid (32 colblocks of 128, 8 b, S), block 256 = 4 waves x 32 cols (2 tiles).
// BK=128 keys/iter; per iter: 16 QK mfma16 + 8 ones-l mfma32 + 32 PV mfma32,
// one barrier, 4 GLDS DMA, 4 f b128 loads, vmcnt(4) counted wait.
// ah LDS reads pipelined one PAIR ahead; QK interleaved between PAIRs.

#define LDAH(V0, V1, V2, V3, HP)                                                \
    half8_t V0 = *(const half8_t*)(HP);                                         \
    half8_t V1 = *(const half8_t*)((HP) + 1024);                                \
    half8_t V2 = *(const half8_t*)((HP) + 2048);                                \
    half8_t V3 = *(const half8_t*)((HP) + 3072);

#define QK(F, N)                                                                \
    float4_t N##A0, N##B0, N##A1, N##B1;                                        \
    {                                                                           \
        half4_t a0 = __builtin_shufflevector(F, F, 0, 1, 2, 3);                 \
        half4_t a1 = __builtin_shufflevector(F, F, 4, 5, 6, 7);                 \
        __builtin_amdgcn_s_setprio(1);                                          \
        N##A0 = mfma16(a0, gfA, z4);                                            \
        N##B0 = mfma16(a0, gfB, z4);                                            \
        N##A1 = mfma16(a1, gfA, z4);                                            \
        N##B1 = mfma16(a1, gfB, z4);                                            \
        __builtin_amdgcn_s_setprio(0);                                          \
    }

// h-frag params H0..H3 so N##A0 etc. paste with LITERAL tokens (R20 lesson)
#define PAIRC(N, H0, H1, H2, H3)                                                \
    {                                                                           \
        float eA0 = fexp2(N##A0[0]), eA1 = fexp2(N##A0[1]),                     \
              eA2 = fexp2(N##A0[2]), eA3 = fexp2(N##A0[3]);                     \
        float oA0 = fexp2(N##A1[0]), oA1 = fexp2(N##A1[1]),                     \
              oA2 = fexp2(N##A1[2]), oA3 = fexp2(N##A1[3]);                     \
        float eB0 = fexp2(N##B0[0]), eB1 = fexp2(N##B0[1]),                     \
              eB2 = fexp2(N##B0[2]), eB3 = fexp2(N##B0[3]);                     \
        float oB0 = fexp2(N##B1[0]), oB1 = fexp2(N##B1[1]),                     \
              oB2 = fexp2(N##B1[2]), oB3 = fexp2(N##B1[3]);                     \
        uintx4 puA = {__builtin_bit_cast(unsigned int, pkcvt(eA0, eA1)),        \
                      __builtin_bit_cast(unsigned int, pkcvt(eA2, eA3)),        \
                      __builtin_bit_cast(unsigned int, pkcvt(oA0, oA1)),        \
                      __builtin_bit_cast(unsigned int, pkcvt(oA2, oA3))};       \
        uintx4 puB = {__builtin_bit_cast(unsigned int, pkcvt(eB0, eB1)),        \
                      __builtin_bit_cast(unsigned int, pkcvt(eB2, eB3)),        \
                      __builtin_bit_cast(unsigned int, pkcvt(oB0, oB1)),        \
                      __builtin_bit_cast(unsigned int, pkcvt(oB2, oB3))};       \
        half8_t pA8 = __builtin_bit_cast(half8_t, puA);                         \
        half8_t pB8 = __builtin_bit_cast(half8_t, puB);                         \
        __builtin_amdgcn_s_setprio(1);                                          \
        accLA = mfma32(ones8, pA8, accLA);                                      \
        accLB = mfma32(ones8, pB8, accLB);                                      \
        accA[0] = mfma32(H0, pA8, accA[0]); accB[0] = mfma32(H0, pB8, accB[0]); \
        accA[1] = mfma32(H1, pA8, accA[1]); accB[1] = mfma32(H1, pB8, accB[1]); \
        accA[2] = mfma32(H2, pA8, accA[2]); accB[2] = mfma32(H2, pB8, accB[2]); \
        accA[3] = mfma32(H3, pA8, accA[3]); accB[3] = mfma32(H3, pB8, accB[3]); \
        __builtin_amdgcn_s_setprio(0);                                          \
    }

template<int NT>
__global__ __launch_bounds__(256) void attn_kernel(
    const __half* __restrict__ fTR, const __half* __restrict__ gT16,
    const __half* __restrict__ hM,
    __half* __restrict__ Pacc, float* __restrict__ Lsum)
{
    __shared__ __align__(16) _Float16 hl[2][8192];  // 2 x 16 KB, [group][ch][64]
    const int tid   = threadIdx.x;
    const int w     = tid >> 6;
    const int lane  = tid & 63;
    const int q     = lane >> 4;
    const int ml    = lane & 15;
    const int m7    = ml & 7;
    const int b     = blockIdx.y;
    const int split = blockIdx.z;
    const int colA  = blockIdx.x * 128 + w * 16 + ml;
    const int colB  = colA + 64;

    half4_t gfA = *(const half4_t*)(gT16 + ((size_t)((b << 12) + colA)) * 16 + q * 4);
    half4_t gfB = *(const half4_t*)(gT16 + ((size_t)((b << 12) + colB)) * 16 + q * 4);

    float4_t accA[4], accB[4];
#pragma unroll
    for (int cg = 0; cg < 4; cg++) {
        accA[cg] = (float4_t){0.f, 0.f, 0.f, 0.f};
        accB[cg] = (float4_t){0.f, 0.f, 0.f, 0.f};
    }
    float4_t accLA = (float4_t){0.f, 0.f, 0.f, 0.f};
    float4_t accLB = (float4_t){0.f, 0.f, 0.f, 0.f};
    const half8_t ones8 = {(_Float16)1.0f, (_Float16)1.0f, (_Float16)1.0f,
                           (_Float16)1.0f, (_Float16)1.0f, (_Float16)1.0f,
                           (_Float16)1.0f, (_Float16)1.0f};
    const float4_t z4 = (float4_t){0.f, 0.f, 0.f, 0.f};

    const int k64 = split * NT * 2;        // first 64-key group index

    // DMA staging: lane-linear LDS dest (tid*16 B), XOR-swizzled global source.
    const int ch0  = tid >> 3;             // 0..31 (part0); part1 adds 32
    const int gsw  = (tid & 7) ^ (ch0 & 7);
    const __half* hs0 = hM + ((size_t)(b * 64 + ch0) << 12) + (size_t)k64 * 64 + gsw * 8;
    const __half* hs1 = hs0 + ((size_t)32 << 12);
    const __half* fptr = fTR + ((size_t)b << 16) + (size_t)(k64 * 16 + ml) * 64 + q * 16;

    // read-side swizzled group offsets (halves)
    const int gxa = ((q ^ m7) << 3);
    const int gxb = (((4 + q) ^ m7) << 3);

    // ---- prologue: DMA 128-key tile 0 + both f records; full drain once ----
    GLDS(hs0,      &hl[0][tid * 8]);
    GLDS(hs1,      &hl[0][2048 + tid * 8]);
    GLDS(hs0 + 64, &hl[0][4096 + tid * 8]);
    GLDS(hs1 + 64, &hl[0][6144 + tid * 8]);
    half8_t f01 = *(const half8_t*)fptr;
    half8_t f23 = *(const half8_t*)(fptr + 8);
    half8_t f45 = *(const half8_t*)(fptr + 1024);
    half8_t f67 = *(const half8_t*)(fptr + 1032);
    __syncthreads();

    const __half* hn0 = hs0 + 128;
    const __half* hn1 = hs1 + 128;

#pragma unroll 1
    for (int kt = 0; kt < NT; kt++) {
        const _Float16* hbA = &hl[kt & 1][ml << 6];
        const _Float16* hbB = hbA + 4096;

        // ---- pipelined body: LDAH one PAIR ahead; QK interleaved ----
        LDAH(a00, a01, a02, a03, hbA + gxa)
        QK(f01, s)

        // issue 4 GLDS for tile kt+1 (vmcnt order: [G x4][f x4])
        if (kt + 1 < NT) {
            _Float16* nb = &hl[(kt + 1) & 1][0];
            GLDS(hn0,      nb + tid * 8);
            GLDS(hn1,      nb + 2048 + tid * 8);
            GLDS(hn0 + 64, nb + 4096 + tid * 8);
            GLDS(hn1 + 64, nb + 6144 + tid * 8);
            hn0 += 128;
            hn1 += 128;
        }

        LDAH(a10, a11, a12, a13, hbA + gxb)
        QK(f23, t)

        PAIRC(s, a00, a01, a02, a03)

        LDAH(a20, a21, a22, a23, hbB + gxa)

        PAIRC(t, a10, a11, a12, a13)

        QK(f45, u)
        LDAH(a30, a31, a32, a33, hbB + gxb)

        PAIRC(u, a20, a21, a22, a23)

        QK(f67, v)
        // prefetch next iter's f records (after all f consumed)
        if (kt + 1 < NT) {
            f01 = *(const half8_t*)(fptr + 2048);
            f23 = *(const half8_t*)(fptr + 2056);
            f45 = *(const half8_t*)(fptr + 3072);
            f67 = *(const half8_t*)(fptr + 3080);
            fptr += 2048;
        }

        PAIRC(v, a30, a31, a32, a33)

        if (kt + 1 < NT) {
            WAITVM4_BAR();   // retires the 4 tile DMAs; f loads stay in flight
        }
    }

    // ---- store UNNORMALIZED partials + l (from ones-MFMA accumulator) ----
    __half* pa = Pacc + (((size_t)(split * 8 + b) * 64) << 12);
#pragma unroll
    for (int cg = 0; cg < 4; cg++)
#pragma unroll
        for (int r = 0; r < 4; r++) {
            int ch = cg * 16 + q * 4 + r;
            pa[((size_t)ch << 12) + colA] = __float2half(accA[cg][r]);
            pa[((size_t)ch << 12) + colB] = __float2half(accB[cg][r]);
        }
    if (q == 0) {
        Lsum[((size_t)(split * 8 + b) << 12) + colA] = accLA[0];
        Lsum[((size_t)(split * 8 + b) << 12) + colB] = accLB[0];
    }
}

// ---------------- merge ------------------------------------------------------
// grid (64 col-tiles, 8 b, 4 ch-groups of 16), block 256 = 16 ch x 16 col-quads.
template<int S>
__global__ __launch_bounds__(256) void merge_kernel(
    const __half* __restrict__ Pacc, const float* __restrict__ Lsum,
    const float* __restrict__ x, const float* __restrict__ gammap,
    float* __restrict__ out)
{
    __shared__ float invL[64];
    const int tid  = threadIdx.x;
    const int c4   = tid & 15;
    const int chh  = tid >> 4;
    const int b    = blockIdx.y;
    const int col0 = blockIdx.x * 64;
    const int ch   = blockIdx.z * 16 + chh;

    if (tid < 64) {
        float L = 0.f;
#pragma unroll
        for (int s = 0; s < S; s++)
            L += Lsum[((size_t)(s * 8 + b) << 12) + col0 + tid];
        invL[tid] = gammap[0] / L;
    }
    __syncthreads();

    const int cc = c4 * 4;
    const size_t base = (((size_t)b * 64 + ch) << 12) + col0 + cc;
    float4 xv = *(const float4*)(x + base);
    float o0 = 0.f, o1 = 0.f, o2 = 0.f, o3 = 0.f;
#pragma unroll
    for (int s = 0; s < S; s++) {
        half4_t pv = *(const half4_t*)(Pacc +
            (((size_t)(s * 8 + b) * 64 + ch) << 12) + col0 + cc);
        o0 += (float)pv[0];
        o1 += (float)pv[1];
        o2 += (float)pv[2];
        o3 += (float)pv[3];
    }
    float4 ov;
    ov.x = o0 * invL[cc]     + xv.x;
    ov.y = o1 * invL[cc + 1] + xv.y;
    ov.z = o2 * invL[cc + 2] + xv.z;
    ov.w = o3 * invL[cc + 3] + xv.w;
    *(float4*)(out + base) = ov;
}

extern "C" void kernel_launch(void* const* d_in, const int* in_sizes, int n_in,
                              void* d_out, int out_size, void* d_ws, size_t ws_size,
                              hipStream_t stream) {
    const float* x     = (const float*)d_in[0];
    const float* Wq    = (const float*)d_in[1];
    const float* bq    = (const float*)d_in[2];
    const float* Wk    = (const float*)d_in[3];
    const float* bk    = (const float*)d_in[4];
    const float* Wv    = (const float*)d_in[5];
    const float* bv    = (const float*)d_in[6];
    const float* gamma = (const float*)d_in[7];
    float* out = (float*)d_out;

    const size_t fr_bytes  = (size_t)8 * 65536 * 2;             // 1 MB (fTR, 4 q-slots)
    const size_t g_bytes   = (size_t)8 * NTOK * 16 * 2;         // 1 MB
    const size_t hM_bytes  = (size_t)8 * 64 * NTOK * 2;         // 4 MB
    const size_t pa_split  = (size_t)8 * 64 * NTOK * 2;         // 4 MB per split
    const size_t l_split   = (size_t)8 * NTOK * sizeof(float);  // 128 KB per split
    const size_t base_need = fr_bytes + g_bytes + hM_bytes;

    int S = 1;
    if (ws_size >= base_need + 2 * (pa_split + l_split)) S = 2;

    char* p = (char*)d_ws;
    __half* fTR  = (__half*)p;  p += fr_bytes;
    __half* gT16 = (__half*)p;  p += g_bytes;
    __half* hM   = (__half*)p;  p += hM_bytes;
    __half* Pacc = (__half*)p;  p += (size_t)S * pa_split;
    float*  Lsum = (float*)p;

    proj_kernel<<<dim3(64, 8), 320, 0, stream>>>(x, Wq, bq, Wk, bk, Wv, bv,
                                                 fTR, gT16, hM);
    if (S == 2) {
        attn_kernel<16><<<dim3(32, 8, 2), 256, 0, stream>>>(fTR, gT16, hM, Pacc, Lsum);
        merge_kernel<2><<<dim3(64, 8, 4), 256, 0, stream>>>(Pacc, Lsum, x, gamma, out);
    } else {
        attn_kernel<32><<<dim3(32, 8, 1), 256, 0, stream>>>(fTR, gT16, hM, Pacc, Lsum);
        merge_kernel<1><<<dim3(64, 8, 4), 256, 0, stream>>>(Pacc, Lsum, x, gamma, out);
    }
}